// Round 1
// baseline (715.156 us; speedup 1.0000x reference)
//
#include <hip/hip_runtime.h>
#include <hip/hip_bf16.h>

// Problem constants (B=32, L=256 -> 8192 tokens)
#define N_TOK   8192
#define DMODEL  256
#define NFEAT   8
#define DFEAT   64
#define DIN     320     // DMODEL + DFEAT
#define DRTR    256
#define NE      8
#define DH      512
#define TB      32      // tokens per router block
#define TE      32      // tokens per expert tile

// d_out layout (floats): [stage_delta 8192*256][gate_weights 8192*8][gate_logits 8192*8]
#define OUT_GATEW  (N_TOK*DMODEL)
#define OUT_LOGITS (N_TOK*DMODEL + N_TOK*NE)

__device__ __forceinline__ float gelu_tanh(float v){
  // jax.nn.gelu(approximate=True)
  float u = 0.7978845608028654f * (v + 0.044715f * v * v * v);
  return 0.5f * v * (1.0f + tanhf(u));
}

__global__ void k_init(int* __restrict__ cnts){
  if (threadIdx.x < NE) cnts[threadIdx.x] = 0;
}

__global__ __launch_bounds__(256) void k_router(
    const float* __restrict__ hidden, const float* __restrict__ feat,
    const float* __restrict__ Wf, const float* __restrict__ bfe,
    const float* __restrict__ Wr1, const float* __restrict__ br1,
    const float* __restrict__ Wr2, const float* __restrict__ br2,
    float* __restrict__ out,
    int* __restrict__ cnts, unsigned* __restrict__ lists, float* __restrict__ topw)
{
  __shared__ float x_lds[TB*DIN];       // [t][i], reads are wave-broadcast
  __shared__ float hr_lds[TB*257];      // pad 257 so logit-phase reads spread banks
  __shared__ float lg_lds[TB*NE];
  const int tid = threadIdx.x;
  const int t0 = blockIdx.x * TB;

  // zero this block's chunk of stage_delta (re-poisoned to 0xAA before each call)
  {
    float4 z = make_float4(0.f,0.f,0.f,0.f);
    float4* dst = ((float4*)out) + (size_t)blockIdx.x*2048 + tid;
    #pragma unroll
    for (int r=0;r<8;r++) dst[r*256] = z;
  }
  // stage hidden -> x_lds[:, 0:256]
  {
    int lane = tid & 63, tq = tid >> 6;
    #pragma unroll
    for (int r=0;r<8;r++){
      int t = tq + r*4;
      float4 h4 = ((const float4*)(hidden + (size_t)(t0+t)*DMODEL))[lane];
      ((float4*)(x_lds + t*DIN))[lane] = h4;
    }
  }
  // feat embedding -> x_lds[:, 256:320]
  #pragma unroll
  for (int rep=0;rep<8;rep++){
    int idx = rep*256 + tid;            // 32 tokens * 64 cols
    int t = idx >> 6, j = idx & 63;
    float acc = bfe[j];
    #pragma unroll
    for (int f=0; f<NFEAT; f++) acc += feat[(size_t)(t0+t)*NFEAT + f] * Wf[f*DFEAT + j];
    x_lds[t*DIN + DMODEL + j] = acc;
  }
  __syncthreads();
  // hr = gelu(x @ Wr1 + br1) : thread = (j-pair jg, token-half th), float2 math
  {
    const int jg = tid & 127;
    const int th = tid >> 7;
    float2 b = ((const float2*)br1)[jg];
    float2 acc[16];
    #pragma unroll
    for (int t=0;t<16;t++) acc[t] = b;
    #pragma unroll 2
    for (int i=0;i<DIN;i++){
      float2 w2 = ((const float2*)(Wr1 + (size_t)i*DRTR))[jg];
      #pragma unroll
      for (int t=0;t<16;t++){
        float xv = x_lds[(th*16+t)*DIN + i];
        acc[t].x += xv*w2.x; acc[t].y += xv*w2.y;
      }
    }
    #pragma unroll
    for (int t=0;t<16;t++){
      hr_lds[(th*16+t)*257 + jg*2]     = gelu_tanh(acc[t].x);
      hr_lds[(th*16+t)*257 + jg*2 + 1] = gelu_tanh(acc[t].y);
    }
  }
  __syncthreads();
  // gate logits: thread = (t = tid>>3, e = tid&7); TEMP == 1.0
  {
    int t = tid >> 3, e = tid & 7;
    float acc = br2[e];
    for (int i=0;i<DRTR;i++) acc += hr_lds[t*257 + i] * Wr2[i*NE + e];
    out[OUT_LOGITS + (size_t)(t0+t)*NE + e] = acc;
    lg_lds[t*NE + e] = acc;
  }
  __syncthreads();
  // top-2 (lax.top_k tie-break: lowest index first -> strict '>'), softmax over top-2
  if (tid < TB){
    int t = tid;
    float v1 = lg_lds[t*NE]; int i1 = 0;
    #pragma unroll
    for (int e=1;e<NE;e++){ float v = lg_lds[t*NE+e]; if (v > v1){ v1 = v; i1 = e; } }
    float v2 = -3.4e38f; int i2 = -1;
    #pragma unroll
    for (int e=0;e<NE;e++){
      if (e == i1) continue;
      float v = lg_lds[t*NE+e]; if (v > v2){ v2 = v; i2 = e; }
    }
    float d   = expf(v2 - v1);          // in (0,1], stable
    float inv = 1.0f/(1.0f + d);
    float w1 = inv, w2 = d*inv;
    #pragma unroll
    for (int e=0;e<NE;e++){
      float gv = (e==i1) ? w1 : ((e==i2) ? w2 : 0.f);
      out[OUT_GATEW + (size_t)(t0+t)*NE + e] = gv;
    }
    int p1 = atomicAdd(&cnts[i1], 1);
    lists[i1*N_TOK + p1] = (unsigned)(((t0+t)<<1));
    int p2 = atomicAdd(&cnts[i2], 1);
    lists[i2*N_TOK + p2] = (unsigned)(((t0+t)<<1) | 1);
    topw[(t0+t)*2]   = w1;
    topw[(t0+t)*2+1] = w2;
  }
}

__global__ __launch_bounds__(256) void k_expert(
    const float* __restrict__ hidden, const float* __restrict__ feat,
    const float* __restrict__ Wf, const float* __restrict__ bfe,
    const int* __restrict__ cnts, const unsigned* __restrict__ lists,
    const float* __restrict__ topw,
    const float* __restrict__ We1, const float* __restrict__ be1,
    const float* __restrict__ We2, const float* __restrict__ be2,
    float* __restrict__ out)
{
  __shared__ float x_lds[TE*DIN];     // 40960 B
  __shared__ float he_lds[TE*DH];     // 65536 B
  __shared__ int   tok_lds[TE];
  __shared__ float w_lds[TE];

  const int e    = blockIdx.x >> 8;   // 256 tiles per expert (worst case 8192 tokens)
  const int tile = blockIdx.x & 255;
  const int cnt  = cnts[e];
  const int start = tile * TE;
  if (start >= cnt) return;           // uniform early-exit, no barrier yet
  const int nt  = min(TE, cnt - start);
  const int tid = threadIdx.x;

  if (tid < TE){
    if (tid < nt){
      unsigned ent = lists[e*N_TOK + start + tid];
      int tok = (int)(ent >> 1);
      tok_lds[tid] = tok;
      w_lds[tid]   = topw[tok*2 + (ent & 1)];
    } else { tok_lds[tid] = -1; w_lds[tid] = 0.f; }
  }
  __syncthreads();
  // gather x = concat(hidden[tok], feat_emb[tok]) into LDS (recomputed, no ws round-trip)
  {
    int lane = tid & 63, tq = tid >> 6;
    #pragma unroll
    for (int r=0;r<8;r++){
      int t = tq + r*4;
      int tok = tok_lds[t];
      float4 h4 = make_float4(0.f,0.f,0.f,0.f);
      if (tok >= 0) h4 = ((const float4*)(hidden + (size_t)tok*DMODEL))[lane];
      ((float4*)(x_lds + t*DIN))[lane] = h4;
    }
  }
  #pragma unroll
  for (int rep=0;rep<8;rep++){
    int idx = rep*256 + tid;
    int t = idx >> 6, j = idx & 63;
    int tok = tok_lds[t];
    float acc = 0.f;
    if (tok >= 0){
      acc = bfe[j];
      #pragma unroll
      for (int f=0; f<NFEAT; f++) acc += feat[(size_t)tok*NFEAT + f] * Wf[f*DFEAT + j];
    }
    x_lds[t*DIN + DMODEL + j] = acc;
  }
  __syncthreads();

  const int hg = tid & 127;   // phase1: h = hg*4 + {0..3}; phase2: o = hg*2 + {0,1}
  const int th = tid >> 7;    // token half: tokens th*16 .. th*16+15
  // phase 1: he = gelu(x @ We1[e] + be1[e])
  {
    const float* W1 = We1 + (size_t)e*DIN*DH;
    float4 b1 = ((const float4*)(be1 + (size_t)e*DH))[hg];
    float2 acc[16][2];
    #pragma unroll
    for (int t=0;t<16;t++){ acc[t][0] = make_float2(b1.x,b1.y); acc[t][1] = make_float2(b1.z,b1.w); }
    #pragma unroll 2
    for (int i=0;i<DIN;i++){
      float4 w4 = ((const float4*)(W1 + (size_t)i*DH))[hg];   // coalesced 1KB/wave
      #pragma unroll
      for (int t=0;t<16;t++){
        float xv = x_lds[(th*16+t)*DIN + i];                  // wave-broadcast LDS read
        acc[t][0].x += xv*w4.x; acc[t][0].y += xv*w4.y;
        acc[t][1].x += xv*w4.z; acc[t][1].y += xv*w4.w;
      }
    }
    #pragma unroll
    for (int t=0;t<16;t++){
      float4 o4 = make_float4(gelu_tanh(acc[t][0].x), gelu_tanh(acc[t][0].y),
                              gelu_tanh(acc[t][1].x), gelu_tanh(acc[t][1].y));
      ((float4*)(he_lds + (size_t)(th*16+t)*DH))[hg] = o4;    // conflict-free b128
    }
  }
  __syncthreads();
  // phase 2: eo = he @ We2[e] + be2[e]; accumulate gate*eo into stage_delta
  {
    const float* W2 = We2 + (size_t)e*DH*DMODEL;
    float2 acc[16];
    #pragma unroll
    for (int t=0;t<16;t++) acc[t] = make_float2(0.f,0.f);
    #pragma unroll 2
    for (int h=0;h<DH;h++){
      float2 w2 = ((const float2*)(W2 + (size_t)h*DMODEL))[hg];
      #pragma unroll
      for (int t=0;t<16;t++){
        float hv = he_lds[(th*16+t)*DH + h];                  // wave-broadcast
        acc[t].x += hv*w2.x; acc[t].y += hv*w2.y;
      }
    }
    float2 b2 = ((const float2*)(be2 + (size_t)e*DMODEL))[hg];
    #pragma unroll
    for (int t=0;t<16;t++){
      int tt = th*16 + t;
      if (tt < nt){
        int tok  = tok_lds[tt];
        float w  = w_lds[tt];
        atomicAdd(out + (size_t)tok*DMODEL + hg*2,     w*(acc[t].x + b2.x));
        atomicAdd(out + (size_t)tok*DMODEL + hg*2 + 1, w*(acc[t].y + b2.y));
      }
    }
  }
}

extern "C" void kernel_launch(void* const* d_in, const int* in_sizes, int n_in,
                              void* d_out, int out_size, void* d_ws, size_t ws_size,
                              hipStream_t stream)
{
  (void)in_sizes; (void)n_in; (void)out_size; (void)ws_size;
  const float* hidden = (const float*)d_in[0];
  const float* feat   = (const float*)d_in[1];
  const float* Wf     = (const float*)d_in[2];
  const float* bfe    = (const float*)d_in[3];
  const float* Wr1    = (const float*)d_in[4];
  const float* br1    = (const float*)d_in[5];
  const float* Wr2    = (const float*)d_in[6];
  const float* br2    = (const float*)d_in[7];
  const float* We1    = (const float*)d_in[8];
  const float* be1    = (const float*)d_in[9];
  const float* We2    = (const float*)d_in[10];
  const float* be2    = (const float*)d_in[11];
  float* out = (float*)d_out;

  // workspace layout: [cnts 8*int][pad][lists 8*8192*u32][topw 16384*f32]  (~328 KB)
  char* ws = (char*)d_ws;
  int*      cnts  = (int*)ws;
  unsigned* lists = (unsigned*)(ws + 256);
  float*    topw  = (float*)(ws + 256 + NE*N_TOK*4);

  hipLaunchKernelGGL(k_init, dim3(1), dim3(64), 0, stream, cnts);
  hipLaunchKernelGGL(k_router, dim3(N_TOK/TB), dim3(256), 0, stream,
                     hidden, feat, Wf, bfe, Wr1, br1, Wr2, br2,
                     out, cnts, lists, topw);
  hipLaunchKernelGGL(k_expert, dim3(NE*256), dim3(256), 0, stream,
                     hidden, feat, Wf, bfe, cnts, lists, topw,
                     We1, be1, We2, be2, out);
}

// Round 2
// 485.964 us; speedup vs baseline: 1.4716x; 1.4716x over previous
//
#include <hip/hip_runtime.h>
#include <hip/hip_bf16.h>

// Problem constants (B=32, L=256 -> 8192 tokens)
#define N_TOK   8192
#define DMODEL  256
#define NFEAT   8
#define DFEAT   64
#define DIN     320     // DMODEL + DFEAT
#define DRTR    256
#define NE      8
#define DH      512
#define TB      32      // tokens per router block
#define TE      32      // tokens per expert tile

// d_out layout (floats): [stage_delta 8192*256][gate_weights 8192*8][gate_logits 8192*8]
#define OUT_GATEW  (N_TOK*DMODEL)
#define OUT_LOGITS (N_TOK*DMODEL + N_TOK*NE)

__device__ __forceinline__ float gelu_tanh(float v){
  // jax.nn.gelu(approximate=True)
  float u = 0.7978845608028654f * (v + 0.044715f * v * v * v);
  return 0.5f * v * (1.0f + tanhf(u));
}

__global__ void k_init(int* __restrict__ cnts){
  if (threadIdx.x < NE) cnts[threadIdx.x] = 0;
}

// Router: 32 tokens/block, 256 threads.
// LDS plan (union): smem[10240] floats (40 KB).
//   phase A: x[t][320]  (stride 320)
//   phase B: hr[t][260] (stride 260 -> float4-aligned, banks spread by t*4)
// Total LDS ~42 KB -> 3 blocks/CU (12 waves/CU).
__global__ __launch_bounds__(256, 3) void k_router(
    const float* __restrict__ hidden, const float* __restrict__ feat,
    const float* __restrict__ Wf, const float* __restrict__ bfe,
    const float* __restrict__ Wr1, const float* __restrict__ br1,
    const float* __restrict__ Wr2, const float* __restrict__ br2,
    float* __restrict__ out,
    int* __restrict__ cnts, unsigned* __restrict__ lists, float* __restrict__ topw)
{
  __shared__ float smem[TB*DIN];      // 40960 B
  __shared__ float lg_lds[TB*NE];
  const int tid = threadIdx.x;
  const int t0 = blockIdx.x * TB;

  // zero this block's chunk of stage_delta (d_out re-poisoned to 0xAA each call)
  {
    float4 z = make_float4(0.f,0.f,0.f,0.f);
    float4* dst = ((float4*)out) + (size_t)blockIdx.x*2048 + tid;
    #pragma unroll
    for (int r=0;r<8;r++) dst[r*256] = z;
  }
  // stage hidden -> x[:, 0:256]
  {
    int lane = tid & 63, tq = tid >> 6;
    #pragma unroll
    for (int r=0;r<8;r++){
      int t = tq + r*4;
      float4 h4 = ((const float4*)(hidden + (size_t)(t0+t)*DMODEL))[lane];
      ((float4*)(smem + t*DIN))[lane] = h4;
    }
  }
  // feature embedding -> x[:, 256:320]
  #pragma unroll
  for (int rep=0;rep<8;rep++){
    int idx = rep*256 + tid;            // 32 tokens * 64 cols
    int t = idx >> 6, j = idx & 63;
    float acc = bfe[j];
    #pragma unroll
    for (int f=0; f<NFEAT; f++) acc += feat[(size_t)(t0+t)*NFEAT + f] * Wf[f*DFEAT + j];
    smem[t*DIN + DMODEL + j] = acc;
  }
  __syncthreads();

  // hr = gelu(x @ Wr1 + br1): thread = (j-pair jg, token-half th)
  const int jg = tid & 127;
  const int th = tid >> 7;
  float2 acc[16];
  {
    float2 b = ((const float2*)br1)[jg];
    #pragma unroll
    for (int t=0;t<16;t++) acc[t] = b;
    const float2* W1 = ((const float2*)Wr1) + jg;   // row stride = 128 float2

    auto fma_chunk = [&](int i4, const float2 (&w)[4]){
      #pragma unroll
      for (int t=0;t<16;t++){
        float4 xv = ((const float4*)smem)[(th*16+t)*80 + i4];   // broadcast b128
        acc[t].x += xv.x*w[0].x + xv.y*w[1].x + xv.z*w[2].x + xv.w*w[3].x;
        acc[t].y += xv.x*w[0].y + xv.y*w[1].y + xv.z*w[2].y + xv.w*w[3].y;
      }
    };
    float2 w[4];
    #pragma unroll
    for (int r=0;r<4;r++) w[r] = W1[r*128];
    for (int i4=0;i4<79;i4++){            // software-pipelined weight prefetch
      float2 wn[4];
      #pragma unroll
      for (int r=0;r<4;r++) wn[r] = W1[(i4*4+4+r)*128];
      fma_chunk(i4, w);
      #pragma unroll
      for (int r=0;r<4;r++) w[r] = wn[r];
    }
    fma_chunk(79, w);
  }
  __syncthreads();    // x region now dead
  #pragma unroll
  for (int t=0;t<16;t++){
    smem[(th*16+t)*260 + jg*2]     = gelu_tanh(acc[t].x);
    smem[(th*16+t)*260 + jg*2 + 1] = gelu_tanh(acc[t].y);
  }
  __syncthreads();
  // gate logits: thread = (t = tid>>3, e = tid&7); TEMP == 1.0
  {
    int t = tid >> 3, e = tid & 7;
    float a0=0.f, a1=0.f, a2=0.f, a3=0.f;
    for (int i4=0;i4<64;i4++){
      float4 h4 = *((const float4*)(smem + t*260 + i4*4));
      a0 += h4.x * Wr2[(i4*4+0)*NE + e];
      a1 += h4.y * Wr2[(i4*4+1)*NE + e];
      a2 += h4.z * Wr2[(i4*4+2)*NE + e];
      a3 += h4.w * Wr2[(i4*4+3)*NE + e];
    }
    float lg = br2[e] + ((a0+a1)+(a2+a3));
    out[OUT_LOGITS + (size_t)(t0+t)*NE + e] = lg;
    lg_lds[t*NE + e] = lg;
  }
  __syncthreads();
  // top-2 (lax.top_k tie-break: lowest index wins -> strict '>'), softmax over top-2
  if (tid < TB){
    int t = tid;
    float v1 = lg_lds[t*NE]; int i1 = 0;
    #pragma unroll
    for (int e=1;e<NE;e++){ float v = lg_lds[t*NE+e]; if (v > v1){ v1 = v; i1 = e; } }
    float v2 = -3.4e38f; int i2 = -1;
    #pragma unroll
    for (int e=0;e<NE;e++){
      if (e == i1) continue;
      float v = lg_lds[t*NE+e]; if (v > v2){ v2 = v; i2 = e; }
    }
    float d   = expf(v2 - v1);          // in (0,1], stable
    float inv = 1.0f/(1.0f + d);
    float w1 = inv, w2 = d*inv;
    #pragma unroll
    for (int e=0;e<NE;e++){
      float gv = (e==i1) ? w1 : ((e==i2) ? w2 : 0.f);
      out[OUT_GATEW + (size_t)(t0+t)*NE + e] = gv;
    }
    int p1 = atomicAdd(&cnts[i1], 1);
    lists[i1*N_TOK + p1] = (unsigned)(((t0+t)<<1));
    int p2 = atomicAdd(&cnts[i2], 1);
    lists[i2*N_TOK + p2] = (unsigned)(((t0+t)<<1) | 1);
    topw[(t0+t)*2]   = w1;
    topw[(t0+t)*2+1] = w2;
  }
}

// Expert: 32 token-slots/tile, 256 threads.
// LDS plan (union): smem[TE*DH] floats (64 KB).
//   phase A: x[t][320] in first 40 KB; phase B: he[t][512].
// Total LDS ~65.8 KB -> 2 blocks/CU (8 waves/CU), was 1.
__global__ __launch_bounds__(256, 2) void k_expert(
    const float* __restrict__ hidden, const float* __restrict__ feat,
    const float* __restrict__ Wf, const float* __restrict__ bfe,
    const int* __restrict__ cnts, const unsigned* __restrict__ lists,
    const float* __restrict__ topw,
    const float* __restrict__ We1, const float* __restrict__ be1,
    const float* __restrict__ We2, const float* __restrict__ be2,
    float* __restrict__ out)
{
  __shared__ float smem[TE*DH];       // 65536 B (union: x then he)
  __shared__ int   tok_lds[TE];
  __shared__ float w_lds[TE];

  const int e    = blockIdx.x >> 8;   // 256 tiles per expert (worst case)
  const int tile = blockIdx.x & 255;
  const int cnt  = cnts[e];
  const int start = tile * TE;
  if (start >= cnt) return;           // uniform early-exit before any barrier
  const int nt  = min(TE, cnt - start);
  const int tid = threadIdx.x;

  if (tid < TE){
    if (tid < nt){
      unsigned ent = lists[e*N_TOK + start + tid];
      int tok = (int)(ent >> 1);
      tok_lds[tid] = tok;
      w_lds[tid]   = topw[tok*2 + (ent & 1)];
    } else { tok_lds[tid] = -1; w_lds[tid] = 0.f; }
  }
  __syncthreads();
  // gather x = concat(hidden[tok], feat_emb[tok]) into LDS
  {
    int lane = tid & 63, tq = tid >> 6;
    #pragma unroll
    for (int r=0;r<8;r++){
      int t = tq + r*4;
      int tok = tok_lds[t];
      float4 h4 = make_float4(0.f,0.f,0.f,0.f);
      if (tok >= 0) h4 = ((const float4*)(hidden + (size_t)tok*DMODEL))[lane];
      ((float4*)(smem + t*DIN))[lane] = h4;
    }
  }
  #pragma unroll
  for (int rep=0;rep<8;rep++){
    int idx = rep*256 + tid;
    int t = idx >> 6, j = idx & 63;
    int tok = tok_lds[t];
    float acc = 0.f;
    if (tok >= 0){
      acc = bfe[j];
      #pragma unroll
      for (int f=0; f<NFEAT; f++) acc += feat[(size_t)tok*NFEAT + f] * Wf[f*DFEAT + j];
    }
    smem[t*DIN + DMODEL + j] = acc;
  }
  __syncthreads();

  const int hg = tid & 127;   // phase1: h = hg*4+{0..3}; phase2: o = hg*2+{0,1}
  const int th = tid >> 7;    // token half
  // phase 1: he = gelu(x @ We1[e] + be1[e]) -- accumulate in regs
  float2 acc1[16][2];
  {
    const float4* W1 = ((const float4*)(We1 + (size_t)e*DIN*DH)) + hg;  // row = 128 float4
    float4 b1 = ((const float4*)(be1 + (size_t)e*DH))[hg];
    #pragma unroll
    for (int t=0;t<16;t++){ acc1[t][0] = make_float2(b1.x,b1.y); acc1[t][1] = make_float2(b1.z,b1.w); }

    auto fma_chunk1 = [&](int i4, const float4 (&w)[4]){
      #pragma unroll
      for (int t=0;t<16;t++){
        float4 xv = ((const float4*)smem)[(th*16+t)*80 + i4];   // broadcast b128
        acc1[t][0].x += xv.x*w[0].x + xv.y*w[1].x + xv.z*w[2].x + xv.w*w[3].x;
        acc1[t][0].y += xv.x*w[0].y + xv.y*w[1].y + xv.z*w[2].y + xv.w*w[3].y;
        acc1[t][1].x += xv.x*w[0].z + xv.y*w[1].z + xv.z*w[2].z + xv.w*w[3].z;
        acc1[t][1].y += xv.x*w[0].w + xv.y*w[1].w + xv.z*w[2].w + xv.w*w[3].w;
      }
    };
    float4 w[4];
    #pragma unroll
    for (int r=0;r<4;r++) w[r] = W1[r*128];
    for (int i4=0;i4<79;i4++){            // prefetch next 4 W1 rows under 256 FMAs
      float4 wn[4];
      #pragma unroll
      for (int r=0;r<4;r++) wn[r] = W1[(i4*4+4+r)*128];
      fma_chunk1(i4, w);
      #pragma unroll
      for (int r=0;r<4;r++) w[r] = wn[r];
    }
    fma_chunk1(79, w);
  }
  __syncthreads();    // x region dead; reuse as he
  #pragma unroll
  for (int t=0;t<16;t++){
    float4 o4 = make_float4(gelu_tanh(acc1[t][0].x), gelu_tanh(acc1[t][0].y),
                            gelu_tanh(acc1[t][1].x), gelu_tanh(acc1[t][1].y));
    ((float4*)(smem + (size_t)(th*16+t)*DH))[hg] = o4;   // conflict-free b128
  }
  __syncthreads();
  // phase 2: eo = he @ We2[e] + be2[e]; accumulate gate*eo into stage_delta
  {
    const float2* W2 = ((const float2*)(We2 + (size_t)e*DH*DMODEL)) + hg; // row = 128 float2
    float2 acc2[16];
    #pragma unroll
    for (int t=0;t<16;t++) acc2[t] = make_float2(0.f,0.f);

    auto fma_chunk2 = [&](int h4i, const float2 (&u)[4]){
      #pragma unroll
      for (int t=0;t<16;t++){
        float4 hv = ((const float4*)smem)[(th*16+t)*128 + h4i];  // broadcast b128
        acc2[t].x += hv.x*u[0].x + hv.y*u[1].x + hv.z*u[2].x + hv.w*u[3].x;
        acc2[t].y += hv.x*u[0].y + hv.y*u[1].y + hv.z*u[2].y + hv.w*u[3].y;
      }
    };
    float2 u[4];
    #pragma unroll
    for (int r=0;r<4;r++) u[r] = W2[r*128];
    for (int h4i=0;h4i<127;h4i++){
      float2 un[4];
      #pragma unroll
      for (int r=0;r<4;r++) un[r] = W2[(h4i*4+4+r)*128];
      fma_chunk2(h4i, u);
      #pragma unroll
      for (int r=0;r<4;r++) u[r] = un[r];
    }
    fma_chunk2(127, u);

    float2 b2 = ((const float2*)(be2 + (size_t)e*DMODEL))[hg];
    #pragma unroll
    for (int t=0;t<16;t++){
      int tt = th*16 + t;
      if (tt < nt){
        int tok  = tok_lds[tt];
        float w  = w_lds[tt];
        atomicAdd(out + (size_t)tok*DMODEL + hg*2,     w*(acc2[t].x + b2.x));
        atomicAdd(out + (size_t)tok*DMODEL + hg*2 + 1, w*(acc2[t].y + b2.y));
      }
    }
  }
}

extern "C" void kernel_launch(void* const* d_in, const int* in_sizes, int n_in,
                              void* d_out, int out_size, void* d_ws, size_t ws_size,
                              hipStream_t stream)
{
  (void)in_sizes; (void)n_in; (void)out_size; (void)ws_size;
  const float* hidden = (const float*)d_in[0];
  const float* feat   = (const float*)d_in[1];
  const float* Wf     = (const float*)d_in[2];
  const float* bfe    = (const float*)d_in[3];
  const float* Wr1    = (const float*)d_in[4];
  const float* br1    = (const float*)d_in[5];
  const float* Wr2    = (const float*)d_in[6];
  const float* br2    = (const float*)d_in[7];
  const float* We1    = (const float*)d_in[8];
  const float* be1    = (const float*)d_in[9];
  const float* We2    = (const float*)d_in[10];
  const float* be2    = (const float*)d_in[11];
  float* out = (float*)d_out;

  // workspace: [cnts 8*int][pad][lists 8*8192*u32][topw 16384*f32]
  char* ws = (char*)d_ws;
  int*      cnts  = (int*)ws;
  unsigned* lists = (unsigned*)(ws + 256);
  float*    topw  = (float*)(ws + 256 + NE*N_TOK*4);

  hipLaunchKernelGGL(k_init, dim3(1), dim3(64), 0, stream, cnts);
  hipLaunchKernelGGL(k_router, dim3(N_TOK/TB), dim3(256), 0, stream,
                     hidden, feat, Wf, bfe, Wr1, br1, Wr2, br2,
                     out, cnts, lists, topw);
  hipLaunchKernelGGL(k_expert, dim3(NE*256), dim3(256), 0, stream,
                     hidden, feat, Wf, bfe, cnts, lists, topw,
                     We1, be1, We2, be2, out);
}